// Round 10
// baseline (282.939 us; speedup 1.0000x reference)
//
#include <hip/hip_runtime.h>
#include <math.h>

// EGNN fused kernel, round 10: re-decomposition to kill the register wall.
// Evidence r3-r9: 112 persistent arch-VGPRs of weight frags kept every 4-wave
// variant at the spill edge (WRITE_SIZE 45-366MB = scratch, not output).
// Now: 512 threads / 8 waves, each wave owns 16 output cols ->
//   weights 56 VGPR/wave, persistent ~78, peak ~120 < 128 cap
//   __launch_bounds__(512,4): 4 waves/SIMD (2 blocks/CU), 2x occupancy.
// Phase structure = r9 (4 barriers/tile):
//  ph1 GEMM1(F)->P1 | ph2 GEMM2(P1)->macc,mask->P2 |
//  ph3 stage-loads; e-partials(P2); stage-writes; GEMM3(P2)->P1 |
//  ph4 e-shfl + m_i (macc dies); GEMM4(P1)->racc; shift partials in-register.

#define BB    2
#define NN    512
#define HDIM  64
#define UDIM  128
#define JT    64
#define NTILE (NN / JT)
#define FP    72    // F row pitch (ushort), 144B
#define PP    136   // P row pitch (ushort), 272B
#define NW    8     // waves per block

typedef float f32x4 __attribute__((ext_vector_type(4)));
typedef short s16x8 __attribute__((ext_vector_type(8)));

__device__ __forceinline__ ushort f2bf(float f) {          // setup-path only
    union { float f; unsigned u; } v; v.f = f;
    return (ushort)((v.u + 0x7FFFu + ((v.u >> 16) & 1u)) >> 16);
}
__device__ __forceinline__ unsigned pk2(float lo, float hi) {  // v_cvt_pk_bf16_f32
    unsigned r;
    asm("v_cvt_pk_bf16_f32 %0, %1, %2" : "=v"(r) : "v"(lo), "v"(hi));
    return r;
}
__device__ __forceinline__ ushort f2bf1(float a) { return (ushort)pk2(a, a); }
__device__ __forceinline__ float bf2f(ushort s) {
    union { unsigned u; float f; } v; v.u = ((unsigned)s) << 16; return v.f;
}
__device__ __forceinline__ f32x4 MFMA(s16x8 a, s16x8 b, f32x4 c) {
    return __builtin_amdgcn_mfma_f32_16x16x32_bf16(a, b, c, 0, 0, 0);
}
__device__ __forceinline__ float eluf(float v) { return v > 0.f ? v : __expf(v) - 1.f; }

// single-column B-frag gather: dst[s] holds W[32s+8q+ii][uc]
__device__ __forceinline__ void load_wfrags1(const float* __restrict__ W, int q, int uc,
                                             s16x8 (&dst)[4]) {
#pragma unroll
    for (int s = 0; s < 4; ++s) {
        s16x8 r;
#pragma unroll
        for (int ii = 0; ii < 8; ++ii)
            r[ii] = (short)f2bf(W[(32 * s + 8 * q + ii) * UDIM + uc]);
        dst[s] = r;
    }
}

// acc[m] += A[16m+l15][k] * wB[s] over k; 16 (or 8) MFMAs
template <int KSTEPS, int PITCH>
__device__ __forceinline__ void gemm_P(const ushort* __restrict__ P, const s16x8 (&wB)[KSTEPS],
                                       int l15, int q, f32x4 (&acc)[4]) {
    __builtin_amdgcn_s_setprio(1);
#pragma unroll
    for (int s = 0; s < KSTEPS; ++s) {
        s16x8 a[4];
#pragma unroll
        for (int m = 0; m < 4; ++m)
            a[m] = *(const s16x8*)(P + (16 * m + l15) * PITCH + 32 * s + 8 * q);
#pragma unroll
        for (int m = 0; m < 4; ++m)
            acc[m] = MFMA(a[m], wB[s], acc[m]);
    }
    __builtin_amdgcn_s_setprio(0);
}

template <bool ELU>
__device__ __forceinline__ void store_P(ushort* __restrict__ P, const f32x4 (&v)[4],
                                        int q, int uc) {
#pragma unroll
    for (int m = 0; m < 4; ++m)
#pragma unroll
        for (int r = 0; r < 4; ++r) {
            float a = v[m][r];
            if (ELU) a = eluf(a);
            P[(16 * m + 4 * q + r) * PP + uc] = f2bf1(a);
        }
}

__global__ __launch_bounds__(512, 4) void egnn_mfma(
    const float* __restrict__ x, const float* __restrict__ h,
    const float* __restrict__ We1, const float* __restrict__ be1,
    const float* __restrict__ We2, const float* __restrict__ be2,
    const float* __restrict__ Winf, const float* __restrict__ binf,
    const float* __restrict__ Wx1, const float* __restrict__ bx1,
    const float* __restrict__ Wx2, const float* __restrict__ bx2,
    const float* __restrict__ Wx3, const float* __restrict__ bx3,
    const float* __restrict__ Wh1, const float* __restrict__ bh1,
    const float* __restrict__ Wh2, const float* __restrict__ bh2,
    const float* __restrict__ Wout, const float* __restrict__ bout,
    float* __restrict__ out) {
    __shared__ ushort F[2][JT][FP];   // double-buffered feat tile (h_j bf16)
    __shared__ ushort P1[JT][PP];
    __shared__ ushort P2[JT][PP];
    __shared__ float normL[2][JT];
    __shared__ float diffL[2][JT][3];
    __shared__ float rpartE[NW][JT];
    __shared__ float bias1L[UDIM];
    __shared__ float WinfL[UDIM];
    __shared__ float shiftL[NW][3];
    __shared__ float catL[UDIM + HDIM];
    __shared__ float th1[UDIM], th2[UDIM];

    const int bi = blockIdx.x;
    const int b  = bi >> 9;
    const int i  = bi & (NN - 1);
    const int tid  = threadIdx.x;
    const int lane = tid & 63;
    const int w    = tid >> 6;          // 0..7
    const int l15  = lane & 15;
    const int q    = lane >> 4;
    const int uc   = 16 * w + l15;      // this lane's single output column
    const int jr   = tid >> 3, k08 = (tid & 7) * 8;   // staging: 64 rows x 8 floats

    // ---- weight fragments (56 VGPRs, block-lifetime) ----
    s16x8 wB1[2];                     // We1 rows 1..64 (h_j part), col uc
#pragma unroll
    for (int s = 0; s < 2; ++s) {
        s16x8 r;
#pragma unroll
        for (int ii = 0; ii < 8; ++ii)
            r[ii] = (short)f2bf(We1[(1 + 32 * s + 8 * q + ii) * UDIM + uc]);
        wB1[s] = r;
    }
    s16x8 wB2[4], wB3[4], wB4[4];
    load_wfrags1(We2, q, uc, wB2);
    load_wfrags1(Wx1, q, uc, wB3);
    load_wfrags1(Wx2, q, uc, wB4);

    if (tid < UDIM) {
        WinfL[tid] = Winf[tid];
        float s = be1[tid];
        const float* hi = &h[(b * NN + i) * HDIM];
#pragma unroll 8
        for (int k = 0; k < HDIM; ++k)
            s = fmaf(hi[k], We1[(1 + HDIM + k) * UDIM + tid], s);
        bias1L[tid] = s;              // be1 + h_i @ We1[65:129]
    }
    const float w0n = We1[uc];        // norm row of We1
    const float b2n = be2[uc];
    const float bqn = bx1[uc];
    const float brn = bx2[uc];
    const float wx3n = Wx3[uc];
    const float binf0 = binf[0], bx30 = bx3[0];
    const float xi0 = x[(b * NN + i) * 3 + 0];
    const float xi1 = x[(b * NN + i) * 3 + 1];
    const float xi2 = x[(b * NN + i) * 3 + 2];

    // ---- prologue: stage tile 0 into buffer 0 (512 threads, 8 floats each) ----
    {
        const float* hp = &h[(b * NN + jr) * HDIM + k08];
        const float4 f0 = *(const float4*)hp;
        const float4 f1 = *(const float4*)(hp + 4);
        uint4 pv;
        pv.x = pk2(f0.x, f0.y); pv.y = pk2(f0.z, f0.w);
        pv.z = pk2(f1.x, f1.y); pv.w = pk2(f1.z, f1.w);
        *(uint4*)&F[0][jr][k08] = pv;
        if (tid < JT) {
            const int j = tid;
            float d0 = x[(b * NN + j) * 3 + 0] - xi0;
            float d1 = x[(b * NN + j) * 3 + 1] - xi1;
            float d2 = x[(b * NN + j) * 3 + 2] - xi2;
            if (j == i) { d0 = 0.f; d1 = 0.f; d2 = 0.f; }
            diffL[0][tid][0] = d0; diffL[0][tid][1] = d1; diffL[0][tid][2] = d2;
            normL[0][tid] = sqrtf(d0 * d0 + d1 * d1 + d2 * d2);
        }
    }
    __syncthreads();                  // bias1L / WinfL / tile-0 staging visible
    const float b1n = bias1L[uc];

    float mi = 0.f;
    float sh0 = 0.f, sh1 = 0.f, sh2 = 0.f;   // per-thread shift partials

    for (int t = 0; t < NTILE; ++t) {
        const int cur = t & 1, nxt = cur ^ 1;
        const int j0 = t * JT;
        const bool more = (t + 1 < NTILE);

        // ---- ph1: GEMM1 -> P1 ----
        f32x4 acc[4];
#pragma unroll
        for (int m = 0; m < 4; ++m)
#pragma unroll
            for (int r = 0; r < 4; ++r)
                acc[m][r] = fmaf(normL[cur][16 * m + 4 * q + r], w0n, b1n);
        gemm_P<2, FP>(&F[cur][0][0], wB1, l15, q, acc);
        store_P<true>(&P1[0][0], acc, q, uc);
        __syncthreads();

        // ---- ph2: GEMM2 -> m_ij (masked) -> P2 ----
        f32x4 macc[4];
#pragma unroll
        for (int m = 0; m < 4; ++m)
#pragma unroll
            for (int r = 0; r < 4; ++r) macc[m][r] = b2n;
        gemm_P<4, PP>(&P1[0][0], wB2, l15, q, macc);
#pragma unroll
        for (int m = 0; m < 4; ++m)
#pragma unroll
            for (int r = 0; r < 4; ++r)
                if (j0 + 16 * m + 4 * q + r == i) macc[m][r] = 0.f;
        store_P<false>(&P2[0][0], macc, q, uc);
        __syncthreads();

        // ---- ph3: stage loads; e-partials; stage writes; GEMM3 -> P1 ----
        {
            // e-partials first (independent; each wave-slice does 16-col dot)
            const int jj = tid & 63, sl = tid >> 6, u0 = sl * 16;
            const ushort* pr = &P2[jj][u0];
            float p = 0.f;
#pragma unroll
            for (int cc = 0; cc < 2; ++cc) {
                const s16x8 mv = *(const s16x8*)(pr + 8 * cc);
#pragma unroll
                for (int c = 0; c < 8; ++c)
                    p = fmaf(bf2f((ushort)mv[c]), WinfL[u0 + 8 * cc + c], p);
            }
            rpartE[sl][jj] = p;
        }
        if (more) {
            const float* hp = &h[(b * NN + j0 + JT + jr) * HDIM + k08];
            const float4 f0 = *(const float4*)hp;
            const float4 f1 = *(const float4*)(hp + 4);
            float sxd0 = 0.f, sxd1 = 0.f, sxd2 = 0.f;
            if (tid < JT) {
                const int j = j0 + JT + tid;
                sxd0 = x[(b * NN + j) * 3 + 0] - xi0;
                sxd1 = x[(b * NN + j) * 3 + 1] - xi1;
                sxd2 = x[(b * NN + j) * 3 + 2] - xi2;
                if (j == i) { sxd0 = 0.f; sxd1 = 0.f; sxd2 = 0.f; }
            }
            uint4 pv;
            pv.x = pk2(f0.x, f0.y); pv.y = pk2(f0.z, f0.w);
            pv.z = pk2(f1.x, f1.y); pv.w = pk2(f1.z, f1.w);
            *(uint4*)&F[nxt][jr][k08] = pv;
            if (tid < JT) {
                diffL[nxt][tid][0] = sxd0; diffL[nxt][tid][1] = sxd1; diffL[nxt][tid][2] = sxd2;
                normL[nxt][tid] = sqrtf(sxd0 * sxd0 + sxd1 * sxd1 + sxd2 * sxd2);
            }
        }
        f32x4 qacc[4];
#pragma unroll
        for (int m = 0; m < 4; ++m)
#pragma unroll
            for (int r = 0; r < 4; ++r) qacc[m][r] = bqn;
        gemm_P<4, PP>(&P2[0][0], wB3, l15, q, qacc);
        store_P<true>(&P1[0][0], qacc, q, uc);
        __syncthreads();

        // ---- ph4: e via shfl + m_i (macc dies); GEMM4 -> racc; shift ----
        float ev;
        {
            float es = binf0;
#pragma unroll
            for (int p = 0; p < NW; ++p) es += rpartE[p][lane];
            ev = 1.f / (1.f + __expf(-es));
        }
#pragma unroll
        for (int m = 0; m < 4; ++m)
#pragma unroll
            for (int r = 0; r < 4; ++r) {
                const float e = __shfl(ev, 16 * m + 4 * q + r);
                mi = fmaf(macc[m][r], e, mi);     // macc[row==i] already zeroed
            }
        f32x4 racc[4];
#pragma unroll
        for (int m = 0; m < 4; ++m)
#pragma unroll
            for (int r = 0; r < 4; ++r) racc[m][r] = brn;
        gemm_P<4, PP>(&P1[0][0], wB4, l15, q, racc);
#pragma unroll
        for (int m = 0; m < 4; ++m)
#pragma unroll
            for (int r = 0; r < 4; ++r) {
                const int row = 16 * m + 4 * q + r;
                float p = eluf(racc[m][r]) * wx3n;
                if (w == 0 && l15 == 0) p += bx30;     // bx3 once per row
                // row==i masked by diffL==0
                sh0 = fmaf(p, diffL[cur][row][0], sh0);
                sh1 = fmaf(p, diffL[cur][row][1], sh1);
                sh2 = fmaf(p, diffL[cur][row][2], sh2);
            }
        __syncthreads();
    }

    // ---- m_i cross-q reduce -> catL ----
    {
        float v = mi;
        v += __shfl_xor(v, 16); v += __shfl_xor(v, 32);
        if (lane < 16) catL[uc] = v;
    }
    // ---- shift: 64-lane butterfly, then cross-wave via LDS ----
    {
#pragma unroll
        for (int d = 1; d < 64; d <<= 1) {
            sh0 += __shfl_xor(sh0, d);
            sh1 += __shfl_xor(sh1, d);
            sh2 += __shfl_xor(sh2, d);
        }
        if (lane == 0) { shiftL[w][0] = sh0; shiftL[w][1] = sh1; shiftL[w][2] = sh2; }
    }
    if (tid >= 128 && tid < 128 + HDIM)
        catL[UDIM + tid - 128] = h[(b * NN + i) * HDIM + (tid - 128)];
    __syncthreads();

    if (tid < 3) {
        const float inv = 1.f / (float)(NN - 1);
        float s = 0.f;
#pragma unroll
        for (int p = 0; p < NW; ++p) s += shiftL[p][tid];
        out[(b * NN + i) * 3 + tid] = x[(b * NN + i) * 3 + tid] + s * inv;
    }

    // ---- h-MLP epilogue (fp32) ----
    if (tid < UDIM) {
        float s = bh1[tid];
        for (int k = 0; k < UDIM + HDIM; ++k) s = fmaf(catL[k], Wh1[k * UDIM + tid], s);
        th1[tid] = eluf(s);
    }
    __syncthreads();
    if (tid < UDIM) {
        float s = bh2[tid];
        for (int k = 0; k < UDIM; ++k) s = fmaf(th1[k], Wh2[k * UDIM + tid], s);
        th2[tid] = s;
    }
    __syncthreads();
    if (tid < HDIM) {
        float s = bout[tid];
        for (int k = 0; k < UDIM; ++k) s = fmaf(th2[k], Wout[k * HDIM + tid], s);
        out[BB * NN * 3 + (b * NN + i) * HDIM + tid] = s;
    }
}

extern "C" void kernel_launch(void* const* d_in, const int* in_sizes, int n_in,
                              void* d_out, int out_size, void* d_ws, size_t ws_size,
                              hipStream_t stream) {
    const float* x    = (const float*)d_in[0];
    const float* h    = (const float*)d_in[1];
    const float* We1  = (const float*)d_in[2];
    const float* be1  = (const float*)d_in[3];
    const float* We2  = (const float*)d_in[4];
    const float* be2  = (const float*)d_in[5];
    const float* Winf = (const float*)d_in[6];
    const float* binf = (const float*)d_in[7];
    const float* Wx1  = (const float*)d_in[8];
    const float* bx1  = (const float*)d_in[9];
    const float* Wx2  = (const float*)d_in[10];
    const float* bx2  = (const float*)d_in[11];
    const float* Wx3  = (const float*)d_in[12];
    const float* bx3  = (const float*)d_in[13];
    const float* Wh1  = (const float*)d_in[14];
    const float* bh1  = (const float*)d_in[15];
    const float* Wh2  = (const float*)d_in[16];
    const float* bh2  = (const float*)d_in[17];
    const float* Wout = (const float*)d_in[18];
    const float* bout = (const float*)d_in[19];
    float* out = (float*)d_out;

    hipLaunchKernelGGL(egnn_mfma, dim3(BB * NN), dim3(512), 0, stream,
                       x, h, We1, be1, We2, be2, Winf, binf, Wx1, bx1, Wx2, bx2,
                       Wx3, bx3, Wh1, bh1, Wh2, bh2, Wout, bout, out);
}

// Round 11
// 161.586 us; speedup vs baseline: 1.7510x; 1.7510x over previous
//
#include <hip/hip_runtime.h>
#include <math.h>

// EGNN fused kernel, round 11: wave-specialized producer/consumer pipeline.
// Register model (r3-r10 evidence): total regs/wave = 2048/(waves per SIMD)/4;
// weight-resident design needs 256/wave -> 2 waves/SIMD fixed. So win by doing
// MORE per barrier: 8 waves, group A (w0-3) = GEMM1+GEMM2 (48 weight regs),
// group B (w4-7) = GEMM3+GEMM4 (64), arrays OVERLAID (wF,wG) -> 64 allocated.
// Iteration t: A works tile t, B works tile t-1; 2 barriers/tile.
//  ph1: A: e-final(t-1)+m_i; GEMM1->P1a; stage t+1 (F 2-deep, diff/norm 3-deep)
//       B: GEMM3(P2[(t-1)&1]) -> P1b
//  ph2: A: GEMM2->maccK(persists 1 barrier), mask, ->P2[t&1]; e-partials
//          (l15 butterfly) -> rpartE
//       B: GEMM4->racc; phi in-register; per-thread shift partials
// maccK is the only cross-barrier accumulator (AGPR-class, budgeted).

#define BB    2
#define NN    512
#define HDIM  64
#define UDIM  128
#define JT    64
#define NTILE (NN / JT)
#define FP    72    // F row pitch (ushort), 144B
#define PP    136   // P row pitch (ushort), 272B

typedef float f32x4 __attribute__((ext_vector_type(4)));
typedef short s16x8 __attribute__((ext_vector_type(8)));

__device__ __forceinline__ ushort f2bf(float f) {          // setup-path only
    union { float f; unsigned u; } v; v.f = f;
    return (ushort)((v.u + 0x7FFFu + ((v.u >> 16) & 1u)) >> 16);
}
__device__ __forceinline__ unsigned pk2(float lo, float hi) {  // bf16 pair pack
    unsigned r;
    asm("v_cvt_pk_bf16_f32 %0, %1, %2" : "=v"(r) : "v"(lo), "v"(hi));
    return r;
}
__device__ __forceinline__ f32x4 MFMA(s16x8 a, s16x8 b, f32x4 c) {
    return __builtin_amdgcn_mfma_f32_16x16x32_bf16(a, b, c, 0, 0, 0);
}
__device__ __forceinline__ float eluf(float v) { return v > 0.f ? v : __expf(v) - 1.f; }

__device__ __forceinline__ void load_wfrags(const float* __restrict__ W, int q, int uc0,
                                            s16x8 (&dst)[4][2]) {
#pragma unroll
    for (int s = 0; s < 4; ++s)
#pragma unroll
        for (int n = 0; n < 2; ++n) {
            s16x8 r;
#pragma unroll
            for (int ii = 0; ii < 8; ++ii)
                r[ii] = (short)f2bf(W[(32 * s + 8 * q + ii) * UDIM + uc0 + n]);
            dst[s][n] = r;
        }
}

template <int KSTEPS, int PITCH>
__device__ __forceinline__ void gemm_P(const ushort* __restrict__ P, const s16x8 (*wB)[2],
                                       int l15, int q, f32x4 (&acc)[4][2]) {
    __builtin_amdgcn_s_setprio(1);
#pragma unroll
    for (int s = 0; s < KSTEPS; ++s) {
        s16x8 a[4];
#pragma unroll
        for (int m = 0; m < 4; ++m)
            a[m] = *(const s16x8*)(P + (16 * m + l15) * PITCH + 32 * s + 8 * q);
#pragma unroll
        for (int m = 0; m < 4; ++m) {
            acc[m][0] = MFMA(a[m], wB[s][0], acc[m][0]);
            acc[m][1] = MFMA(a[m], wB[s][1], acc[m][1]);
        }
    }
    __builtin_amdgcn_s_setprio(0);
}

template <bool ELU>
__device__ __forceinline__ void store_P(ushort* __restrict__ P, const f32x4 (&v)[4][2],
                                        int q, int uc0) {
#pragma unroll
    for (int m = 0; m < 4; ++m)
#pragma unroll
        for (int r = 0; r < 4; ++r) {
            const int row = 16 * m + 4 * q + r;
            float a = v[m][0][r], c = v[m][1][r];
            if (ELU) { a = eluf(a); c = eluf(c); }
            *(unsigned*)(P + row * PP + uc0) = pk2(a, c);
        }
}

__global__ __launch_bounds__(512, 2) void egnn_ws(
    const float* __restrict__ x, const float* __restrict__ h,
    const float* __restrict__ We1, const float* __restrict__ be1,
    const float* __restrict__ We2, const float* __restrict__ be2,
    const float* __restrict__ Winf, const float* __restrict__ binf,
    const float* __restrict__ Wx1, const float* __restrict__ bx1,
    const float* __restrict__ Wx2, const float* __restrict__ bx2,
    const float* __restrict__ Wx3, const float* __restrict__ bx3,
    const float* __restrict__ Wh1, const float* __restrict__ bh1,
    const float* __restrict__ Wh2, const float* __restrict__ bh2,
    const float* __restrict__ Wout, const float* __restrict__ bout,
    float* __restrict__ out) {
    __shared__ ushort F[2][JT][FP];      // feat tile, 2-deep (h_j bf16)
    __shared__ ushort P1a[JT][PP];       // A-internal: t1
    __shared__ ushort P1b[JT][PP];       // B-internal: h1
    __shared__ ushort P2[2][JT][PP];     // A->B: m_ij, 2-deep
    __shared__ float normL[3][JT];       // 3-deep (write t+1, read t, B reads t-1's diff)
    __shared__ float diffL[3][JT][3];
    __shared__ float rpartE[4][JT];
    __shared__ float bias1L[UDIM];
    __shared__ float shiftL[4][3];
    __shared__ float catL[UDIM + HDIM];
    __shared__ float th1[UDIM], th2[UDIM];

    const int bi = blockIdx.x;
    const int b  = bi >> 9;
    const int i  = bi & (NN - 1);
    const int tid  = threadIdx.x;
    const int lane = tid & 63;
    const int w    = tid >> 6;           // 0..7
    const bool isA = (w < 4);
    const int wg   = w & 3;
    const int l15  = lane & 15;
    const int q    = lane >> 4;
    const int uc0  = 32 * wg + 2 * l15;  // group-local column pair

    // ---- overlaid weight fragments (64 regs/wave allocated) ----
    s16x8 wF[4][2];                      // A: We2 (GEMM2) | B: Wx1 (GEMM3)
    s16x8 wG[4][2];                      // A: [0..1]=We1 rows1..64 (GEMM1) | B: Wx2 (GEMM4)
    if (isA) {
#pragma unroll
        for (int s = 0; s < 2; ++s)
#pragma unroll
            for (int n = 0; n < 2; ++n) {
                s16x8 r;
#pragma unroll
                for (int ii = 0; ii < 8; ++ii)
                    r[ii] = (short)f2bf(We1[(1 + 32 * s + 8 * q + ii) * UDIM + uc0 + n]);
                wG[s][n] = r;
            }
        load_wfrags(We2, q, uc0, wF);
    } else {
        load_wfrags(Wx1, q, uc0, wF);
        load_wfrags(Wx2, q, uc0, wG);
    }

    if (tid < UDIM) {
        float s = be1[tid];
        const float* hi = &h[(b * NN + i) * HDIM];
#pragma unroll 8
        for (int k = 0; k < HDIM; ++k)
            s = fmaf(hi[k], We1[(1 + HDIM + k) * UDIM + tid], s);
        bias1L[tid] = s;                 // be1 + h_i @ We1[65:129]
    }
    // group-specific scalars
    float w0n0 = 0.f, w0n1 = 0.f, b2n0 = 0.f, b2n1 = 0.f, winf0 = 0.f, winf1 = 0.f;
    float bqn0 = 0.f, bqn1 = 0.f, brn0 = 0.f, brn1 = 0.f, wx30 = 0.f, wx31 = 0.f;
    if (isA) {
        w0n0 = We1[uc0]; w0n1 = We1[uc0 + 1];
        b2n0 = be2[uc0]; b2n1 = be2[uc0 + 1];
        winf0 = Winf[uc0]; winf1 = Winf[uc0 + 1];
    } else {
        bqn0 = bx1[uc0]; bqn1 = bx1[uc0 + 1];
        brn0 = bx2[uc0]; brn1 = bx2[uc0 + 1];
        wx30 = Wx3[uc0]; wx31 = Wx3[uc0 + 1];
    }
    const float binf0 = binf[0], bx30 = bx3[0];
    const float xi0 = x[(b * NN + i) * 3 + 0];
    const float xi1 = x[(b * NN + i) * 3 + 1];
    const float xi2 = x[(b * NN + i) * 3 + 2];

    // ---- prologue: stage tile 0 (512 threads, 8 floats each) ----
    {
        const int jr8 = tid >> 3, k08 = (tid & 7) * 8;
        const float* hp = &h[(b * NN + jr8) * HDIM + k08];
        const float4 f0 = *(const float4*)hp;
        const float4 f1 = *(const float4*)(hp + 4);
        uint4 pv;
        pv.x = pk2(f0.x, f0.y); pv.y = pk2(f0.z, f0.w);
        pv.z = pk2(f1.x, f1.y); pv.w = pk2(f1.z, f1.w);
        *(uint4*)&F[0][jr8][k08] = pv;
        if (tid < JT) {
            float d0 = x[(b * NN + tid) * 3 + 0] - xi0;
            float d1 = x[(b * NN + tid) * 3 + 1] - xi1;
            float d2 = x[(b * NN + tid) * 3 + 2] - xi2;
            if (tid == i) { d0 = 0.f; d1 = 0.f; d2 = 0.f; }
            diffL[0][tid][0] = d0; diffL[0][tid][1] = d1; diffL[0][tid][2] = d2;
            normL[0][tid] = sqrtf(d0 * d0 + d1 * d1 + d2 * d2);
        }
    }
    __syncthreads();
    const float b1n0 = isA ? bias1L[uc0] : 0.f;
    const float b1n1 = isA ? bias1L[uc0 + 1] : 0.f;

    f32x4 maccK[4][2];                   // A: m_ij regs, persist ph2(t)->ph1(t+1)
    float mi0 = 0.f, mi1 = 0.f;          // A: m_i accumulators
    float sh0 = 0.f, sh1 = 0.f, sh2 = 0.f;  // B: shift partials

    for (int t = 0; t <= NTILE; ++t) {
        const bool doG1 = (t < NTILE);
        const bool doSt = (t < NTILE - 1);
        const bool doPrev = (t > 0);

        // ================= phase 1 =================
        if (isA) {
            // staging loads for tile t+1 (issued first, consumed at phase end)
            float4 f0, f1, f2, f3;
            float sxd0 = 0.f, sxd1 = 0.f, sxd2 = 0.f;
            const int jr = tid >> 2, k0 = (tid & 3) * 16;
            if (doSt) {
                const float* hp = &h[(b * NN + (t + 1) * JT + jr) * HDIM + k0];
                f0 = *(const float4*)hp;
                f1 = *(const float4*)(hp + 4);
                f2 = *(const float4*)(hp + 8);
                f3 = *(const float4*)(hp + 12);
                if (tid < JT) {
                    const int j = (t + 1) * JT + tid;
                    sxd0 = x[(b * NN + j) * 3 + 0] - xi0;
                    sxd1 = x[(b * NN + j) * 3 + 1] - xi1;
                    sxd2 = x[(b * NN + j) * 3 + 2] - xi2;
                    if (j == i) { sxd0 = 0.f; sxd1 = 0.f; sxd2 = 0.f; }
                }
            }
            // e-finalize tile t-1 + m_i accumulation (maccK already masked)
            if (doPrev) {
                float es = binf0;
#pragma unroll
                for (int p = 0; p < 4; ++p) es += rpartE[p][lane];
                const float ev = 1.f / (1.f + __expf(-es));
#pragma unroll
                for (int m = 0; m < 4; ++m)
#pragma unroll
                    for (int r = 0; r < 4; ++r) {
                        const float e = __shfl(ev, 16 * m + 4 * q + r);
                        mi0 = fmaf(maccK[m][0][r], e, mi0);
                        mi1 = fmaf(maccK[m][1][r], e, mi1);
                    }
            }
            if (doG1) {
                f32x4 acc[4][2];
#pragma unroll
                for (int m = 0; m < 4; ++m)
#pragma unroll
                    for (int r = 0; r < 4; ++r) {
                        const float nrm = normL[t % 3][16 * m + 4 * q + r];
                        acc[m][0][r] = fmaf(nrm, w0n0, b1n0);
                        acc[m][1][r] = fmaf(nrm, w0n1, b1n1);
                    }
                gemm_P<2, FP>(&F[t & 1][0][0], wG, l15, q, acc);
                store_P<true>(&P1a[0][0], acc, q, uc0);
            }
            if (doSt) {
                uint4 pv0, pv1;
                pv0.x = pk2(f0.x, f0.y); pv0.y = pk2(f0.z, f0.w);
                pv0.z = pk2(f1.x, f1.y); pv0.w = pk2(f1.z, f1.w);
                pv1.x = pk2(f2.x, f2.y); pv1.y = pk2(f2.z, f2.w);
                pv1.z = pk2(f3.x, f3.y); pv1.w = pk2(f3.z, f3.w);
                *(uint4*)&F[(t + 1) & 1][jr][k0]     = pv0;
                *(uint4*)&F[(t + 1) & 1][jr][k0 + 8] = pv1;
                if (tid < JT) {
                    const int s3 = (t + 1) % 3;
                    diffL[s3][tid][0] = sxd0; diffL[s3][tid][1] = sxd1; diffL[s3][tid][2] = sxd2;
                    normL[s3][tid] = sqrtf(sxd0 * sxd0 + sxd1 * sxd1 + sxd2 * sxd2);
                }
            }
        } else if (doPrev) {
            // B: GEMM3 on m_ij(t-1) -> P1b
            f32x4 qacc[4][2];
#pragma unroll
            for (int m = 0; m < 4; ++m)
#pragma unroll
                for (int r = 0; r < 4; ++r) { qacc[m][0][r] = bqn0; qacc[m][1][r] = bqn1; }
            gemm_P<4, PP>(&P2[(t - 1) & 1][0][0], wF, l15, q, qacc);
            store_P<true>(&P1b[0][0], qacc, q, uc0);
        }
        __syncthreads();

        // ================= phase 2 =================
        if (isA) {
            if (doG1) {
                const int j0 = t * JT;
#pragma unroll
                for (int m = 0; m < 4; ++m)
#pragma unroll
                    for (int r = 0; r < 4; ++r) { maccK[m][0][r] = b2n0; maccK[m][1][r] = b2n1; }
                gemm_P<4, PP>(&P1a[0][0], wF, l15, q, maccK);
#pragma unroll
                for (int m = 0; m < 4; ++m)
#pragma unroll
                    for (int r = 0; r < 4; ++r)
                        if (j0 + 16 * m + 4 * q + r == i) { maccK[m][0][r] = 0.f; maccK[m][1][r] = 0.f; }
                store_P<false>(&P2[t & 1][0][0], maccK, q, uc0);
                // e-partials: 2-col contribution, butterfly over l15 -> rpartE
                float pe[4][4];
#pragma unroll
                for (int m = 0; m < 4; ++m)
#pragma unroll
                    for (int r = 0; r < 4; ++r)
                        pe[m][r] = maccK[m][0][r] * winf0 + maccK[m][1][r] * winf1;
#pragma unroll
                for (int d = 1; d < 16; d <<= 1)
#pragma unroll
                    for (int m = 0; m < 4; ++m)
#pragma unroll
                        for (int r = 0; r < 4; ++r)
                            pe[m][r] += __shfl_xor(pe[m][r], d);
                if (l15 == 0) {
#pragma unroll
                    for (int m = 0; m < 4; ++m)
#pragma unroll
                        for (int r = 0; r < 4; ++r)
                            rpartE[wg][16 * m + 4 * q + r] = pe[m][r];
                }
            }
        } else if (doPrev) {
            // B: GEMM4 -> racc; phi in-register; shift partials
            f32x4 racc[4][2];
#pragma unroll
            for (int m = 0; m < 4; ++m)
#pragma unroll
                for (int r = 0; r < 4; ++r) { racc[m][0][r] = brn0; racc[m][1][r] = brn1; }
            gemm_P<4, PP>(&P1b[0][0], wG, l15, q, racc);
            const int s3 = (t - 1) % 3;
#pragma unroll
            for (int m = 0; m < 4; ++m)
#pragma unroll
                for (int r = 0; r < 4; ++r) {
                    const int row = 16 * m + 4 * q + r;
                    float p = eluf(racc[m][0][r]) * wx30 + eluf(racc[m][1][r]) * wx31;
                    if (wg == 0 && l15 == 0) p += bx30;   // bx3 once per row
                    // row==i masked by diffL==0
                    sh0 = fmaf(p, diffL[s3][row][0], sh0);
                    sh1 = fmaf(p, diffL[s3][row][1], sh1);
                    sh2 = fmaf(p, diffL[s3][row][2], sh2);
                }
        }
        __syncthreads();
    }

    // ---- epilogue reductions ----
    if (isA) {
        float v0 = mi0, v1 = mi1;
        v0 += __shfl_xor(v0, 16); v0 += __shfl_xor(v0, 32);
        v1 += __shfl_xor(v1, 16); v1 += __shfl_xor(v1, 32);
        if (lane < 16) {
            catL[uc0]     = v0;
            catL[uc0 + 1] = v1;
        }
    } else {
#pragma unroll
        for (int d = 1; d < 64; d <<= 1) {
            sh0 += __shfl_xor(sh0, d);
            sh1 += __shfl_xor(sh1, d);
            sh2 += __shfl_xor(sh2, d);
        }
        if (lane == 0) { shiftL[wg][0] = sh0; shiftL[wg][1] = sh1; shiftL[wg][2] = sh2; }
    }
    if (tid >= 128 && tid < 128 + HDIM)
        catL[UDIM + tid - 128] = h[(b * NN + i) * HDIM + (tid - 128)];
    __syncthreads();

    if (tid < 3) {
        const float inv = 1.f / (float)(NN - 1);
        const float s = shiftL[0][tid] + shiftL[1][tid] + shiftL[2][tid] + shiftL[3][tid];
        out[(b * NN + i) * 3 + tid] = x[(b * NN + i) * 3 + tid] + s * inv;
    }

    // ---- h-MLP epilogue (fp32) ----
    if (tid < UDIM) {
        float s = bh1[tid];
        for (int k = 0; k < UDIM + HDIM; ++k) s = fmaf(catL[k], Wh1[k * UDIM + tid], s);
        th1[tid] = eluf(s);
    }
    __syncthreads();
    if (tid < UDIM) {
        float s = bh2[tid];
        for (int k = 0; k < UDIM; ++k) s = fmaf(th1[k], Wh2[k * UDIM + tid], s);
        th2[tid] = s;
    }
    __syncthreads();
    if (tid < HDIM) {
        float s = bout[tid];
        for (int k = 0; k < UDIM; ++k) s = fmaf(th2[k], Wout[k * HDIM + tid], s);
        out[BB * NN * 3 + (b * NN + i) * HDIM + tid] = s;
    }
}

extern "C" void kernel_launch(void* const* d_in, const int* in_sizes, int n_in,
                              void* d_out, int out_size, void* d_ws, size_t ws_size,
                              hipStream_t stream) {
    const float* x    = (const float*)d_in[0];
    const float* h    = (const float*)d_in[1];
    const float* We1  = (const float*)d_in[2];
    const float* be1  = (const float*)d_in[3];
    const float* We2  = (const float*)d_in[4];
    const float* be2  = (const float*)d_in[5];
    const float* Winf = (const float*)d_in[6];
    const float* binf = (const float*)d_in[7];
    const float* Wx1  = (const float*)d_in[8];
    const float* bx1  = (const float*)d_in[9];
    const float* Wx2  = (const float*)d_in[10];
    const float* bx2  = (const float*)d_in[11];
    const float* Wx3  = (const float*)d_in[12];
    const float* bx3  = (const float*)d_in[13];
    const float* Wh1  = (const float*)d_in[14];
    const float* bh1  = (const float*)d_in[15];
    const float* Wh2  = (const float*)d_in[16];
    const float* bh2  = (const float*)d_in[17];
    const float* Wout = (const float*)d_in[18];
    const float* bout = (const float*)d_in[19];
    float* out = (float*)d_out;

    hipLaunchKernelGGL(egnn_ws, dim3(BB * NN), dim3(512), 0, stream,
                       x, h, We1, be1, We2, be2, Winf, binf, Wx1, bx1, Wx2, bx2,
                       Wx3, bx3, Wh1, bh1, Wh2, bh2, Wout, bout, out);
}